// Round 2
// baseline (710.287 us; speedup 1.0000x reference)
//
#include <hip/hip_runtime.h>

// ExtractSearchWindows: out[b,h,w,rr,tt] = (uint8)Q[b, h+off+ry+ty, w+off+rx+tx],
// Q = input padded by 6; stored as INT32.
//
// R9 theory: all prior variants (R3-R8, ~240-270us kernel) share {stage ->
// barrier -> 5-store burst -> idle}: per-CU outstanding-store bytes average
// ~15-25KB == Little's-law knee -> ~2.9 TB/s, while harness fill (32 pure-store
// waves/CU, stores always in flight) hits 6.25 TB/s on the same buffer with a
// MORE scattered pattern. Fix: (1) 32 waves/CU (1024 persistent blocks x 512
// thr, launch_bounds(512,8), VGPR<=64); (2) stores NEVER awaited: raw s_barrier
// + lgkmcnt(0) only (no __syncthreads -> no vmcnt(0) drain), double-buffered
// patch, next staging load issued BEFORE current stores so the compiler's
// counted vmcnt leaves younger stores in flight; (3) LDS gather hedge: patch
// replicated x4 at 232-int stride (bank shift 8/copy), lane reads copy tid&3.

#define KT 7
#define K2 49
#define MAX_SR 3
#define B_ 2
#define H_ 192
#define W_ 192
#define HW (H_ * W_)
#define PAD 6
#define NT 512
#define RMAX 5              // ceil(2401/512) quads per thread
#define PS 17               // patch row stride within a copy (13 rows used)
#define REP 4               // replicated patch copies
#define CSTR 232            // ints between copies; 232%32=8 -> +8 banks/copy
#define BUFI (REP * CSTR)   // 928 ints per buffer
#define NGROUPS (B_ * H_ * W_ / 4)   // 18432
#define NBLOCKS 1024        // 4 blocks/CU resident (2048 thr/CU)
#define NITER (NGROUPS / NBLOCKS)    // 18
#define TABN (4 * NT * RMAX)         // 10240 entries >= 4*d_max = 9604

typedef int vint4 __attribute__((ext_vector_type(4)));

__device__ __forceinline__ int tab_entry(int jj, int cv, int offset, int d,
                                         int cvmagic) {
    if (jj >= 4 * d) jj = 4 * d - 1;            // clamp inactive tail
    int p_in = (jj >= d) + (jj >= 2 * d) + (jj >= 3 * d);
    int j  = jj - p_in * d;
    int rr = j / K2;                            // const divisor 49
    int tt = j - rr * K2;
    int ry = (rr * cvmagic) >> 16;              // rr / cv  (rr < 49)
    int rx = rr - ry * cv;
    int ty = tt / KT;                           // const divisor 7
    int tx = tt - ty * KT;
    // byte offset into int patch copy 0, incl. pixel-in-group column shift
    return 4 * ((offset + ry + ty) * PS + (offset + rx + tx) + p_in);
}

__global__ __launch_bounds__(256) void tab_kernel(
    int* __restrict__ tab, int cv, int offset, int d, int cvmagic)
{
    int jj = blockIdx.x * 256 + threadIdx.x;
    if (jj < TABN) tab[jj] = tab_entry(jj, cv, offset, d, cvmagic);
}

__global__ __launch_bounds__(NT, 8) void esw_kernel(
    const float* __restrict__ in, int* __restrict__ out,
    const int* __restrict__ tab,
    int cv, int offset, int d, int cvmagic)
{
    __shared__ int patch[2][BUFI + 8];

    const int tid = threadIdx.x;
    const int bid = blockIdx.x;
    const int cshift = (tid & 3) * (CSTR * 4);   // my copy, byte offset

    // Per-thread quad offset table (copy choice baked in).
    vint4 f[RMAX];
    if (tab) {
        #pragma unroll
        for (int r = 0; r < RMAX; ++r) {
            vint4 t = *(const vint4*)(tab + 4 * (tid + NT * r));
            t.x += cshift; t.y += cshift; t.z += cshift; t.w += cshift;
            f[r] = t;
        }
    } else {
        #pragma unroll
        for (int r = 0; r < RMAX; ++r) {
            int j4 = 4 * (tid + NT * r);
            #pragma unroll
            for (int u = 0; u < 4; ++u)
                f[r][u] = tab_entry(j4 + u, cv, offset, d, cvmagic) + cshift;
        }
    }

    // Staging role: thread -> one patch element (dup elem 207 for tid>=208).
    const int sidx = tid < 13 * 16 ? tid : 13 * 16 - 1;
    const int sdy = sidx >> 4;
    const int sdx = sidx & 15;
    const int swa = sdy * PS + sdx;              // int index within a copy

    // Prologue: stage group g0 = bid into buffer 0.
    {
        const int pix0 = 4 * bid;
        const int b   = pix0 / HW;
        const int rem = pix0 - b * HW;
        const int h   = rem / W_;
        const int w   = rem - h * W_;
        int y = h + sdy - PAD;
        int x = w + sdx - PAD;
        int v = 0;
        if ((unsigned)y < (unsigned)H_ && (unsigned)x < (unsigned)W_)
            v = (int)in[b * HW + y * W_ + x];
        #pragma unroll
        for (int c = 0; c < REP; ++c) patch[0][c * CSTR + swa] = v;
    }
    asm volatile("s_waitcnt lgkmcnt(0)" ::: "memory");
    __builtin_amdgcn_sched_barrier(0);
    __builtin_amdgcn_s_barrier();
    __builtin_amdgcn_sched_barrier(0);

    int cur = 0;
    for (int it = 0; it < NITER; ++it) {
        const int g = it * NBLOCKS + bid;        // chip-wide sweeping window
        const int have = (it + 1 < NITER);       // block-uniform

        // A: issue NEXT group's staging load first (older than the stores, so
        // the compiler's counted vmcnt for its use won't drain them).
        int vnext = 0;
        if (have) {
            const int pix0 = 4 * (g + NBLOCKS);
            const int b   = pix0 / HW;
            const int rem = pix0 - b * HW;
            const int h   = rem / W_;
            const int w   = rem - h * W_;
            int y = h + sdy - PAD;
            int x = w + sdx - PAD;
            if ((unsigned)y < (unsigned)H_ && (unsigned)x < (unsigned)W_)
                vnext = (int)in[b * HW + y * W_ + x];
        }

        // B: gather current group from patch[cur], stream stores.
        int* op = out + g * (4 * d);             // <=177M ints, 32-bit safe
        const char* pb = (const char*)&patch[cur][0];
        #pragma unroll
        for (int r = 0; r < RMAX; ++r) {
            int q = tid + NT * r;
            if (q < d) {                         // r<4 full; r=4 masked
                vint4 v;
                v.x = *(const int*)(pb + f[r].x);
                v.y = *(const int*)(pb + f[r].y);
                v.z = *(const int*)(pb + f[r].z);
                v.w = *(const int*)(pb + f[r].w);
                *(vint4*)(op + 4 * q) = v;
            }
        }

        // C: write staged value into the other buffer; only lgkmcnt before the
        // barrier -> outstanding stores are never waited on.
        if (have) {
            int* pn = &patch[cur ^ 1][0];
            #pragma unroll
            for (int c = 0; c < REP; ++c) pn[c * CSTR + swa] = vnext;
            asm volatile("s_waitcnt lgkmcnt(0)" ::: "memory");
            __builtin_amdgcn_sched_barrier(0);
            __builtin_amdgcn_s_barrier();
            __builtin_amdgcn_sched_barrier(0);
            cur ^= 1;
        }
    }
}

extern "C" void kernel_launch(void* const* d_in, const int* in_sizes, int n_in,
                              void* d_out, int out_size, void* d_ws, size_t ws_size,
                              hipStream_t stream) {
    const float* in = (const float*)d_in[0];
    int* out = (int*)d_out;

    // out_size = B*H*W * cv^2 * 49
    int cv2 = out_size / (B_ * H_ * W_ * K2);
    int cv = 1;
    while (cv * cv < cv2) ++cv;
    int offset = MAX_SR - (cv - 1) / 2;
    int d = cv2 * K2;
    int cvmagic = 65536 / cv + 1;

    int* tab = (ws_size >= (size_t)(TABN * sizeof(int))) ? (int*)d_ws : nullptr;
    if (tab)
        tab_kernel<<<(TABN + 255) / 256, 256, 0, stream>>>(tab, cv, offset, d,
                                                           cvmagic);
    esw_kernel<<<NBLOCKS, NT, 0, stream>>>(in, out, tab, cv, offset, d, cvmagic);
}

// Round 3
// 708.535 us; speedup vs baseline: 1.0025x; 1.0025x over previous
//
#include <hip/hip_runtime.h>

// ExtractSearchWindows: out[b,h,w,rr,tt] = (uint8)Q[b, h+off+ry+ty, w+off+rx+tx],
// Q = input padded by 6; stored as INT32.
//
// R10 theory: R3-R9 (four loop shapes, sweeping window, 12/24/32 waves/CU,
// stores-never-drained) ALL land at ~250us kernel -> store side exonerated.
// The shared untouched component: the gather = 4 scattered ds_read_b32 per 16B
// store, whose lane pattern is stride-4 ints -> only 8 distinct banks -> 8-way
// conflict (m136: >=2.94x). R9's x4-replication hedge was arithmetically void
// (bank = (4l+8*(l&3))%32 has lane-period 8 -> same 8 banks). Fix: skew swizzle
// s(e) = e + (e>>2)  (bijective; e=4q+u -> 5q+u). Lane stride becomes 5, coprime
// with 32 -> all banks, 2 lanes/bank = free. Swizzle baked into the offset
// table; staging writes one swizzled slot; gather code unchanged. Structure
// otherwise identical to R9 (1024 persistent blocks x 512 thr, double-buffered
// patch, raw s_barrier + lgkmcnt only, stores never awaited).

#define KT 7
#define K2 49
#define MAX_SR 3
#define B_ 2
#define H_ 192
#define W_ 192
#define HW (H_ * W_)
#define PAD 6
#define NT 512
#define RMAX 5              // ceil(2401/512) quads per thread
#define PS 17               // patch row stride in element space (13 rows used)
#define BUFI 280            // swizzled span: s(219) = 273 -> 280 ints
#define NGROUPS (B_ * H_ * W_ / 4)   // 18432
#define NBLOCKS 1024        // 4 blocks/CU resident (2048 thr/CU)
#define NITER (NGROUPS / NBLOCKS)    // 18
#define TABN (4 * NT * RMAX)         // 10240 entries >= 4*d_max = 9604

typedef int vint4 __attribute__((ext_vector_type(4)));

__device__ __forceinline__ int swz(int e) { return e + (e >> 2); }  // 4q+u -> 5q+u

__device__ __forceinline__ int tab_entry(int jj, int cv, int offset, int d,
                                         int cvmagic) {
    if (jj >= 4 * d) jj = 4 * d - 1;            // clamp inactive tail
    int p_in = (jj >= d) + (jj >= 2 * d) + (jj >= 3 * d);
    int j  = jj - p_in * d;
    int rr = j / K2;                            // const divisor 49
    int tt = j - rr * K2;
    int ry = (rr * cvmagic) >> 16;              // rr / cv  (rr < 49)
    int rx = rr - ry * cv;
    int ty = tt / KT;                           // const divisor 7
    int tx = tt - ty * KT;
    int e = (offset + ry + ty) * PS + (offset + rx + tx) + p_in; // element idx
    return 4 * swz(e);                          // swizzled byte offset
}

__global__ __launch_bounds__(256) void tab_kernel(
    int* __restrict__ tab, int cv, int offset, int d, int cvmagic)
{
    int jj = blockIdx.x * 256 + threadIdx.x;
    if (jj < TABN) tab[jj] = tab_entry(jj, cv, offset, d, cvmagic);
}

__global__ __launch_bounds__(NT, 8) void esw_kernel(
    const float* __restrict__ in, int* __restrict__ out,
    const int* __restrict__ tab,
    int cv, int offset, int d, int cvmagic)
{
    __shared__ int patch[2][BUFI];

    const int tid = threadIdx.x;
    const int bid = blockIdx.x;

    // Per-thread quad offset table (swizzled byte offsets), coalesced dwordx4.
    vint4 f[RMAX];
    if (tab) {
        #pragma unroll
        for (int r = 0; r < RMAX; ++r)
            f[r] = *(const vint4*)(tab + 4 * (tid + NT * r));
    } else {
        #pragma unroll
        for (int r = 0; r < RMAX; ++r) {
            int j4 = 4 * (tid + NT * r);
            #pragma unroll
            for (int u = 0; u < 4; ++u)
                f[r][u] = tab_entry(j4 + u, cv, offset, d, cvmagic);
        }
    }

    // Staging role: thread -> one patch element (dup elem 207 for tid>=208).
    const int sidx = tid < 13 * 16 ? tid : 13 * 16 - 1;
    const int sdy = sidx >> 4;
    const int sdx = sidx & 15;
    const int swa = swz(sdy * PS + sdx);         // swizzled int index

    // Prologue: stage group g0 = bid into buffer 0.
    {
        const int pix0 = 4 * bid;
        const int b   = pix0 / HW;
        const int rem = pix0 - b * HW;
        const int h   = rem / W_;
        const int w   = rem - h * W_;
        int y = h + sdy - PAD;
        int x = w + sdx - PAD;
        int v = 0;
        if ((unsigned)y < (unsigned)H_ && (unsigned)x < (unsigned)W_)
            v = (int)in[b * HW + y * W_ + x];
        patch[0][swa] = v;
    }
    asm volatile("s_waitcnt lgkmcnt(0)" ::: "memory");
    __builtin_amdgcn_sched_barrier(0);
    __builtin_amdgcn_s_barrier();
    __builtin_amdgcn_sched_barrier(0);

    int cur = 0;
    for (int it = 0; it < NITER; ++it) {
        const int g = it * NBLOCKS + bid;        // chip-wide sweeping window
        const int have = (it + 1 < NITER);       // block-uniform

        // A: issue NEXT group's staging load first (older than the stores, so
        // the compiler's counted vmcnt for its use won't drain them).
        int vnext = 0;
        if (have) {
            const int pix0 = 4 * (g + NBLOCKS);
            const int b   = pix0 / HW;
            const int rem = pix0 - b * HW;
            const int h   = rem / W_;
            const int w   = rem - h * W_;
            int y = h + sdy - PAD;
            int x = w + sdx - PAD;
            if ((unsigned)y < (unsigned)H_ && (unsigned)x < (unsigned)W_)
                vnext = (int)in[b * HW + y * W_ + x];
        }

        // B: gather current group from patch[cur], stream stores.
        int* op = out + g * (4 * d);             // <=177M ints, 32-bit safe
        const char* pb = (const char*)&patch[cur][0];
        #pragma unroll
        for (int r = 0; r < RMAX; ++r) {
            int q = tid + NT * r;
            if (q < d) {                         // r<4 full; r=4 masked
                vint4 v;
                v.x = *(const int*)(pb + f[r].x);
                v.y = *(const int*)(pb + f[r].y);
                v.z = *(const int*)(pb + f[r].z);
                v.w = *(const int*)(pb + f[r].w);
                *(vint4*)(op + 4 * q) = v;
            }
        }

        // C: write staged value into the other buffer; only lgkmcnt before the
        // barrier -> outstanding stores are never waited on.
        if (have) {
            patch[cur ^ 1][swa] = vnext;
            asm volatile("s_waitcnt lgkmcnt(0)" ::: "memory");
            __builtin_amdgcn_sched_barrier(0);
            __builtin_amdgcn_s_barrier();
            __builtin_amdgcn_sched_barrier(0);
            cur ^= 1;
        }
    }
}

extern "C" void kernel_launch(void* const* d_in, const int* in_sizes, int n_in,
                              void* d_out, int out_size, void* d_ws, size_t ws_size,
                              hipStream_t stream) {
    const float* in = (const float*)d_in[0];
    int* out = (int*)d_out;

    // out_size = B*H*W * cv^2 * 49
    int cv2 = out_size / (B_ * H_ * W_ * K2);
    int cv = 1;
    while (cv * cv < cv2) ++cv;
    int offset = MAX_SR - (cv - 1) / 2;
    int d = cv2 * K2;
    int cvmagic = 65536 / cv + 1;

    int* tab = (ws_size >= (size_t)(TABN * sizeof(int))) ? (int*)d_ws : nullptr;
    if (tab)
        tab_kernel<<<(TABN + 255) / 256, 256, 0, stream>>>(tab, cv, offset, d,
                                                           cvmagic);
    esw_kernel<<<NBLOCKS, NT, 0, stream>>>(in, out, tab, cv, offset, d, cvmagic);
}

// Round 4
// 693.154 us; speedup vs baseline: 1.0247x; 1.0222x over previous
//
#include <hip/hip_runtime.h>

// ExtractSearchWindows: out[b,h,w,rr,tt] = (uint8)Q[b, h+off+ry+ty, w+off+rx+tx],
// Q = input padded by 6; stored as INT32.
//
// R11 theory: fill hits 6.3 TB/s at 3 waves/CU because each wave streams
// back-to-back stores with ~60KB continuously in flight. All our variants
// (R3-R10, ~250us = 2.8 TB/s) quantize stores into 5-instr bursts separated by
// block-wide barriers + staging, AND the counted vmcnt wait for each
// iteration's staging load forces all older stores to retire (single in-order
// vmcnt counter) -> per-wave store duty cycle ~40% == 2.8/6.3. Fix: one group
// per WAVE with wave-private patch -> ZERO s_barrier in the kernel; each wave
// streams 38 consecutive {tab prefetch, 4 ds_read, dwordx4 store} rounds
// (38KB run) per group, 9 groups back-to-back; offsets from L2-hot global
// table prefetched 1 round ahead (no register table). One small staggered
// vmcnt drain per group per wave (not lockstep). LDS swizzle s(e)=e+(e>>2)
// kept (conflict-free gather). 512 blocks x 256 thr = 2048 waves.

#define KT 7
#define K2 49
#define MAX_SR 3
#define B_ 2
#define H_ 192
#define W_ 192
#define HW (H_ * W_)
#define PAD 6
#define NT 256
#define NBLOCKS 512
#define WPB (NT / 64)                 // 4 waves per block
#define NWAVES (NBLOCKS * WPB)        // 2048; 18432 groups / 2048 = 9 per wave
#define PS 17                         // patch row stride in element space
#define BUFI 280                      // swz(219)=273 -> pad to 280 ints
#define NGROUPS (B_ * H_ * W_ / 4)    // 18432
#define TABQ 2560                     // quads covered by table (>= 64*38+63)
#define TABN (4 * TABQ)               // 10240 ints

typedef int vint4 __attribute__((ext_vector_type(4)));

__device__ __forceinline__ int swz(int e) { return e + (e >> 2); }  // bijective

__device__ __forceinline__ int tab_entry(int jj, int cv, int offset, int d,
                                         int cvmagic) {
    if (jj >= 4 * d) jj = 4 * d - 1;            // clamp inactive tail
    int p_in = (jj >= d) + (jj >= 2 * d) + (jj >= 3 * d);
    int j  = jj - p_in * d;
    int rr = j / K2;                            // const divisor 49
    int tt = j - rr * K2;
    int ry = (rr * cvmagic) >> 16;              // rr / cv  (rr < 49)
    int rx = rr - ry * cv;
    int ty = tt / KT;                           // const divisor 7
    int tx = tt - ty * KT;
    int e = (offset + ry + ty) * PS + (offset + rx + tx) + p_in;
    return 4 * swz(e);                          // swizzled byte offset
}

__global__ __launch_bounds__(256) void tab_kernel(
    int* __restrict__ tab, int cv, int offset, int d, int cvmagic)
{
    int jj = blockIdx.x * 256 + threadIdx.x;
    if (jj < TABN) tab[jj] = tab_entry(jj, cv, offset, d, cvmagic);
}

__global__ __launch_bounds__(NT, 2) void esw_kernel(
    const float* __restrict__ in, int* __restrict__ out,
    const int* __restrict__ tab,
    int cv, int offset, int d, int cvmagic)
{
    __shared__ int patch[WPB][BUFI];

    const int tid  = threadIdx.x;
    const int lane = tid & 63;
    const int wv   = tid >> 6;
    int* const pbuf = patch[wv];                 // wave-private patch
    const char* const pb = (const char*)pbuf;

    const int NR  = (4 * d + 255) >> 8;          // gather rounds (<=38)
    const int wid = blockIdx.x * WPB + wv;

    for (int g = wid; g < NGROUPS; g += NWAVES) {
        // ---- stage the 13x16 neighborhood of this group's 4 pixels ----
        const int pix0 = 4 * g;                  // W%4==0 -> group in one row
        const int b   = pix0 / HW;
        const int rem = pix0 - b * HW;
        const int h   = rem / W_;
        const int w   = rem - h * W_;
        #pragma unroll
        for (int k = 0; k < 4; ++k) {
            int e = lane + 64 * k;               // k<3 full; k==3: lanes<16
            if (e < 13 * 16) {
                int dy = e >> 4, dx = e & 15;
                int y = h + dy - PAD, x = w + dx - PAD;
                int v = 0;
                if ((unsigned)y < (unsigned)H_ && (unsigned)x < (unsigned)W_)
                    v = (int)in[b * HW + y * W_ + x];
                pbuf[swz(dy * PS + dx)] = v;     // counted vmcnt wait (staggered
            }                                    // per-wave, no lockstep)
        }
        asm volatile("s_waitcnt lgkmcnt(0)" ::: "memory");  // patch ready
        // NOTE: no s_barrier anywhere — patch is wave-private.

        // ---- gather + uninterrupted store stream: NR x 1KB per wave ----
        int* op = out + g * (4 * d);             // <=177M ints, 32-bit safe
        if (tab) {
            vint4 t = *(const vint4*)(tab + 4 * lane);           // round 0
            for (int r = 0; r < NR; ++r) {
                // prefetch next round's offsets (64*NR+63 < TABQ always)
                vint4 tn = *(const vint4*)(tab + 4 * (64 * (r + 1) + lane));
                int q = 64 * r + lane;
                if (q < d) {                     // only last round masked
                    vint4 v;
                    v.x = *(const int*)(pb + t.x);
                    v.y = *(const int*)(pb + t.y);
                    v.z = *(const int*)(pb + t.z);
                    v.w = *(const int*)(pb + t.w);
                    *(vint4*)(op + 4 * q) = v;
                }
                t = tn;
            }
        } else {                                 // no-workspace fallback
            for (int r = 0; r < NR; ++r) {
                int q = 64 * r + lane;
                if (q < d) {
                    vint4 v;
                    v.x = *(const int*)(pb + tab_entry(4 * q + 0, cv, offset, d, cvmagic));
                    v.y = *(const int*)(pb + tab_entry(4 * q + 1, cv, offset, d, cvmagic));
                    v.z = *(const int*)(pb + tab_entry(4 * q + 2, cv, offset, d, cvmagic));
                    v.w = *(const int*)(pb + tab_entry(4 * q + 3, cv, offset, d, cvmagic));
                    *(vint4*)(op + 4 * q) = v;
                }
            }
        }
        // DS ops are same-pipe in-order, but be explicit: next group's stage
        // ds_writes must not bypass this group's gather reads.
        asm volatile("s_waitcnt lgkmcnt(0)" ::: "memory");
    }
}

extern "C" void kernel_launch(void* const* d_in, const int* in_sizes, int n_in,
                              void* d_out, int out_size, void* d_ws, size_t ws_size,
                              hipStream_t stream) {
    const float* in = (const float*)d_in[0];
    int* out = (int*)d_out;

    // out_size = B*H*W * cv^2 * 49
    int cv2 = out_size / (B_ * H_ * W_ * K2);
    int cv = 1;
    while (cv * cv < cv2) ++cv;
    int offset = MAX_SR - (cv - 1) / 2;
    int d = cv2 * K2;
    int cvmagic = 65536 / cv + 1;

    int* tab = (ws_size >= (size_t)(TABN * sizeof(int))) ? (int*)d_ws : nullptr;
    if (tab)
        tab_kernel<<<(TABN + 255) / 256, 256, 0, stream>>>(tab, cv, offset, d,
                                                           cvmagic);
    esw_kernel<<<NBLOCKS, NT, 0, stream>>>(in, out, tab, cv, offset, d, cvmagic);
}